// Round 2
// baseline (105.824 us; speedup 1.0000x reference)
//
#include <hip/hip_runtime.h>

typedef __attribute__((ext_vector_type(4))) float f32x4;
typedef __attribute__((ext_vector_type(8))) __bf16 bf16x8;
typedef __attribute__((ext_vector_type(8))) unsigned short ushort8v;
typedef __attribute__((ext_vector_type(4))) unsigned short ushort4v;

#define NGRP  100
#define DDIM  768
#define FDIM  100
#define NCLS  10000
#define NSTEP 12          // 768 / 64
#define NTILE 7           // ceil(112/16) f-tiles
#define WT_G  (FDIM * DDIM)   // 76800 elems per group in Wt[g][f][k]

static __device__ __forceinline__ unsigned short f2bf(float f) {
    __bf16 b = (__bf16)f;   // RNE; compiler pairs into v_cvt_pk_bf16_f32
    return __builtin_bit_cast(unsigned short, b);
}

// ---------------- pre-pass: W (g,d,f) f32 -> Wt (g,f,k=d) bf16 ----------------
__global__ __launch_bounds__(256) void transpose_w(
    const float* __restrict__ W, unsigned short* __restrict__ Wt)
{
    __shared__ unsigned short lds[FDIM * 66];   // [f][r], stride 66 (33 dwords, conflict-free)
    const int b   = blockIdx.x;
    const int g   = b / 12;
    const int d0  = (b % 12) * 64;
    const int tid = threadIdx.x;

    const float* Wg = W + (size_t)g * (DDIM * FDIM) + (size_t)d0 * FDIM;
#pragma unroll
    for (int j = 0; j < 25; ++j) {          // 64 d-rows x 100 f, coalesced
        const int i = tid + j * 256;        // 0..6399
        const int r = i / 100, f = i % 100;
        lds[f * 66 + r] = f2bf(Wg[i]);
    }
    __syncthreads();

    unsigned short* Wo = Wt + (size_t)g * WT_G + d0;
#pragma unroll
    for (int j = 0; j < 7; ++j) {           // 100 f-rows x 16 ushort4 units
        const int u = tid + j * 256;
        const int f = u >> 4, kk = (u & 15) * 4;
        if (f < FDIM) {
            ushort4v v;
            v.x = lds[f * 66 + kk + 0]; v.y = lds[f * 66 + kk + 1];
            v.z = lds[f * 66 + kk + 2]; v.w = lds[f * 66 + kk + 3];
            *(ushort4v*)(Wo + (size_t)f * DDIM + kk) = v;   // coalesced 8B stores
        }
    }
}

// ---------------- main: LDS-free, barrier-free MFMA GEMM ----------------
__global__ __launch_bounds__(256, 2) void gfcp_main(
    const float* __restrict__ H, const unsigned short* __restrict__ Wt,
    const float* __restrict__ Bv, float* __restrict__ Out)
{
    // XCD-bijective swizzle (800 % 8 == 0): all 8 row-blocks of a group on one XCD
    const int bid  = blockIdx.x;
    const int wgid = (bid & 7) * 100 + (bid >> 3);
    const int g    = wgid >> 3;           // group 0..99
    const int m0   = (wgid & 7) * 64;     // row block

    const int tid  = threadIdx.x;
    const int lane = tid & 63;
    const int wv   = tid >> 6;            // wave 0..3 (independent, share B via L1)
    const int r16  = lane & 15;
    const int kg   = lane >> 4;           // 0..3

    const int row = m0 + wv * 16 + r16;
    const float* Ap = H + (size_t)row * (NGRP * DDIM) + (size_t)g * DDIM + kg * 8;

    const unsigned short* Bbase = Wt + (size_t)g * WT_G + kg * 8;
    const unsigned short* Bp[NTILE];
#pragma unroll
    for (int t = 0; t < NTILE; ++t) {
        int f = t * 16 + r16;
        if (f > FDIM - 1) f = FDIM - 1;   // clamp; dup cols land in unsaved acc lanes
        Bp[t] = Bbase + (size_t)f * DDIM;
    }

    f32x4 acc[NTILE];
#pragma unroll
    for (int t = 0; t < NTILE; ++t) acc[t] = (f32x4)(0.0f);

#pragma unroll
    for (int step = 0; step < NSTEP; ++step) {
        const int k0 = step * 64;
        // A fragment: 8 floats at kg*8, 8 more at kg*8+32 (within this 64-K step)
        const f32x4 a0 = *(const f32x4*)(Ap + k0);
        const f32x4 a1 = *(const f32x4*)(Ap + k0 + 4);
        const f32x4 a2 = *(const f32x4*)(Ap + k0 + 32);
        const f32x4 a3 = *(const f32x4*)(Ap + k0 + 36);
        ushort8v u0, u1;
        u0[0] = f2bf(a0[0]); u0[1] = f2bf(a0[1]); u0[2] = f2bf(a0[2]); u0[3] = f2bf(a0[3]);
        u0[4] = f2bf(a1[0]); u0[5] = f2bf(a1[1]); u0[6] = f2bf(a1[2]); u0[7] = f2bf(a1[3]);
        u1[0] = f2bf(a2[0]); u1[1] = f2bf(a2[1]); u1[2] = f2bf(a2[2]); u1[3] = f2bf(a2[3]);
        u1[4] = f2bf(a3[0]); u1[5] = f2bf(a3[1]); u1[6] = f2bf(a3[2]); u1[7] = f2bf(a3[3]);
        const bf16x8 af0 = __builtin_bit_cast(bf16x8, u0);
        const bf16x8 af1 = __builtin_bit_cast(bf16x8, u1);

#pragma unroll
        for (int t = 0; t < NTILE; ++t) {
            const bf16x8 bf = *(const bf16x8*)(Bp[t] + k0);          // imm offset
            acc[t] = __builtin_amdgcn_mfma_f32_16x16x32_bf16(af0, bf, acc[t], 0, 0, 0);
        }
#pragma unroll
        for (int t = 0; t < NTILE; ++t) {
            const bf16x8 bf = *(const bf16x8*)(Bp[t] + k0 + 32);     // imm offset
            acc[t] = __builtin_amdgcn_mfma_f32_16x16x32_bf16(af1, bf, acc[t], 0, 0, 0);
        }
    }

    // epilogue: C/D layout col=lane&15, row=(lane>>4)*4+r
    const int orow  = m0 + wv * 16 + kg * 4;
    const int fbase = g * FDIM;
#pragma unroll
    for (int t = 0; t < NTILE; ++t) {
        const int fc = t * 16 + r16;
        if (fc < FDIM) {
            const float bv = Bv[fbase + fc];
#pragma unroll
            for (int r = 0; r < 4; ++r) {
                Out[(size_t)(orow + r) * NCLS + fbase + fc] = acc[t][r] + bv;
            }
        }
    }
}

extern "C" void kernel_launch(void* const* d_in, const int* in_sizes, int n_in,
                              void* d_out, int out_size, void* d_ws, size_t ws_size,
                              hipStream_t stream) {
    const float* H  = (const float*)d_in[0];   // (512, 100, 768) f32
    const float* W  = (const float*)d_in[1];   // (100, 768, 100) f32
    const float* Bv = (const float*)d_in[2];   // (10000,) f32
    float* Out = (float*)d_out;                // (512, 10000) f32
    unsigned short* Wt = (unsigned short*)d_ws;  // (100, 100, 768) bf16 = 15.36 MB

    transpose_w<<<dim3(1200), dim3(256), 0, stream>>>(W, Wt);
    gfcp_main<<<dim3(800), dim3(256), 0, stream>>>(H, Wt, Bv, Out);
}

// Round 3
// 50.195 us; speedup vs baseline: 2.1083x; 2.1083x over previous
//
#include <hip/hip_runtime.h>

typedef __attribute__((ext_vector_type(4))) float f32x4;
typedef __attribute__((ext_vector_type(8))) __bf16 bf16x8;
typedef __attribute__((ext_vector_type(8))) unsigned short ushort8v;
typedef __attribute__((ext_vector_type(4))) unsigned short ushort4v;

#define NGRP   100
#define DDIM   768
#define FDIM   100
#define NCLS   10000
#define NSTEP  12                       // 768 / 64
#define NTILE  7                        // ceil(112/16) f-tiles
#define NCHUNK 14                       // 7 tiles x 2 k-halves
#define CH_SHORTS 512                   // one chunk: 64 lanes x 8 bf16
#define STEP_SHORTS (NCHUNK * CH_SHORTS)   // 7168 shorts = 14336 B per k-step
#define G_SHORTS (NSTEP * STEP_SHORTS)     // 86016 shorts per group

#define GLOBAL_AS __attribute__((address_space(1)))
#define LDS_AS    __attribute__((address_space(3)))

static __device__ __forceinline__ unsigned short f2bf(float f) {
    __bf16 b = (__bf16)f;   // RNE; pairs into v_cvt_pk_bf16_f32
    return __builtin_bit_cast(unsigned short, b);
}

// ---- pre-pass: W (g,d,f) f32 -> Wt fragment-linear bf16 ----
// Wt[(g*12+step)*14 + c][lane][j] = W[g][step*64 + (c&1)*32 + (lane>>4)*8 + j][min((c>>1)*16 + (lane&15), 99)]
__global__ __launch_bounds__(256) void build_wt(
    const float* __restrict__ W, unsigned short* __restrict__ Wt)
{
    __shared__ unsigned short lt[FDIM * 66];   // [f][d-offset], stride 66 (33 dwords)
    const int b = blockIdx.x, g = b / 12, step = b % 12;
    const int tid = threadIdx.x;

    const float* Wg = W + (size_t)g * (DDIM * FDIM) + (size_t)step * 64 * FDIM;
#pragma unroll
    for (int j = 0; j < 25; ++j) {          // 64 d-rows x 100 f, coalesced reads
        const int i = tid + j * 256;
        const int r = i / 100, f = i % 100;
        lt[f * 66 + r] = f2bf(Wg[i]);
    }
    __syncthreads();

    unsigned short* out = Wt + (size_t)g * G_SHORTS + step * STEP_SHORTS;
#pragma unroll
    for (int j = 0; j < 4; ++j) {
        const int idx = tid + j * 256;      // 0..895 fragment-lane slots
        if (idx < NCHUNK * 64) {
            const int c = idx >> 6, lane = idx & 63;
            const int t = c >> 1, half = c & 1;
            int f = t * 16 + (lane & 15); if (f > FDIM - 1) f = FDIM - 1;
            const int kk = half * 32 + (lane >> 4) * 8;
            const unsigned short* src = &lt[f * 66 + kk];
            ushort8v v;
            v[0]=src[0]; v[1]=src[1]; v[2]=src[2]; v[3]=src[3];
            v[4]=src[4]; v[5]=src[5]; v[6]=src[6]; v[7]=src[7];
            *(ushort8v*)(out + (size_t)idx * 8) = v;    // coalesced 16B stores
        }
    }
}

// ---- main: B via global_load_lds double-buffer, A reg-prefetch, 1 barrier/step ----
__global__ __launch_bounds__(256, 4) void gfcp_main(
    const float* __restrict__ H, const unsigned short* __restrict__ Wt,
    const float* __restrict__ Bv, float* __restrict__ Out)
{
    __shared__ unsigned short Bl[2][STEP_SHORTS];   // 2 x 14336 B = 28.7 KB

    // XCD-bijective swizzle (800 % 8 == 0): a group's 8 row-blocks share one XCD L2
    const int bid  = blockIdx.x;
    const int wgid = (bid & 7) * 100 + (bid >> 3);
    const int g    = wgid >> 3;
    const int m0   = (wgid & 7) * 64;

    const int tid  = threadIdx.x;
    const int lane = tid & 63;
    const int wv   = tid >> 6;
    const int r16  = lane & 15;
    const int kg   = lane >> 4;

    const float* Ap = H + (size_t)(m0 + wv * 16 + r16) * (NGRP * DDIM)
                        + (size_t)g * DDIM + kg * 8;
    const unsigned short* Bg = Wt + (size_t)g * G_SHORTS + lane * 8;

    f32x4 acc[NTILE];
#pragma unroll
    for (int t = 0; t < NTILE; ++t) acc[t] = (f32x4)(0.0f);

    f32x4 a[2][4];   // A prefetch, 2 slots x 16 f32

    auto stage = [&](int buf, int step) {   // 14 x 1KB DMA, split across 4 waves
        const unsigned short* gsrc = Bg + step * STEP_SHORTS;
#pragma unroll
        for (int i = 0; i < 4; ++i) {
            const int c = wv + i * 4;       // wave-uniform chunk id
            if (c < NCHUNK) {
                __builtin_amdgcn_global_load_lds(
                    (const GLOBAL_AS void*)(gsrc + c * CH_SHORTS),
                    (LDS_AS void*)(&Bl[buf][c * CH_SHORTS]),
                    16, 0, 0);
            }
        }
    };
    auto loadA = [&](int slot, int step) {
        const float* p = Ap + step * 64;
        a[slot][0] = *(const f32x4*)(p);
        a[slot][1] = *(const f32x4*)(p + 4);
        a[slot][2] = *(const f32x4*)(p + 32);
        a[slot][3] = *(const f32x4*)(p + 36);
    };
    auto compute = [&](int buf, int slot) {
        const unsigned short* bl = &Bl[buf][0];
#pragma unroll
        for (int s = 0; s < 2; ++s) {
            const f32x4 x = a[slot][2 * s], y = a[slot][2 * s + 1];
            ushort8v u;
            u[0]=f2bf(x[0]); u[1]=f2bf(x[1]); u[2]=f2bf(x[2]); u[3]=f2bf(x[3]);
            u[4]=f2bf(y[0]); u[5]=f2bf(y[1]); u[6]=f2bf(y[2]); u[7]=f2bf(y[3]);
            const bf16x8 af = __builtin_bit_cast(bf16x8, u);
#pragma unroll
            for (int t = 0; t < NTILE; ++t) {
                const ushort8v bu = *(const ushort8v*)(bl + (t * 2 + s) * CH_SHORTS + lane * 8);
                acc[t] = __builtin_amdgcn_mfma_f32_16x16x32_bf16(
                    af, __builtin_bit_cast(bf16x8, bu), acc[t], 0, 0, 0);
            }
        }
    };

    // prologue: A(0), A(1) and B(0) in flight; barrier drains them
    loadA(0, 0);
    loadA(1, 1);
    stage(0, 0);
    __syncthreads();

#pragma unroll
    for (int t = 0; t < NSTEP; ++t) {
        const int cur = t & 1;
        if (t + 1 < NSTEP) stage(cur ^ 1, t + 1);   // issue next-step DMA first
        compute(cur, cur);                          // ds_read + MFMA on current
        if (t + 2 < NSTEP) loadA(cur, t + 2);       // refill freed A slot
        if (t + 1 < NSTEP) __syncthreads();         // drains DMA(t+1) + A(t+2)
    }

    // epilogue: C/D layout col=lane&15, row=(lane>>4)*4+r
    const int orow  = m0 + wv * 16 + kg * 4;
    const int fbase = g * FDIM;
#pragma unroll
    for (int t = 0; t < NTILE; ++t) {
        const int fc = t * 16 + r16;
        if (fc < FDIM) {
            const float bv = Bv[fbase + fc];
#pragma unroll
            for (int r = 0; r < 4; ++r) {
                Out[(size_t)(orow + r) * NCLS + fbase + fc] = acc[t][r] + bv;
            }
        }
    }
}

extern "C" void kernel_launch(void* const* d_in, const int* in_sizes, int n_in,
                              void* d_out, int out_size, void* d_ws, size_t ws_size,
                              hipStream_t stream) {
    const float* H  = (const float*)d_in[0];   // (512, 100, 768) f32
    const float* W  = (const float*)d_in[1];   // (100, 768, 100) f32
    const float* Bv = (const float*)d_in[2];   // (10000,) f32
    float* Out = (float*)d_out;                // (512, 10000) f32
    unsigned short* Wt = (unsigned short*)d_ws; // fragment-linear bf16, 17.2 MB

    build_wt<<<dim3(1200), dim3(256), 0, stream>>>(W, Wt);
    gfcp_main<<<dim3(800), dim3(256), 0, stream>>>(H, Wt, Bv, Out);
}